// Round 10
// baseline (6476.954 us; speedup 1.0000x reference)
//
#include <hip/hip_runtime.h>
#include <hip/hip_bf16.h>

typedef __hip_bfloat16 bf16;
typedef __attribute__((ext_vector_type(8))) short short8;
typedef __attribute__((ext_vector_type(4))) float float4v;

#define B_    1024
#define H_    512
#define G4H   2048
#define F_    32
#define CIN_  4
#define K_    30
#define STRIDE_ 6
#define L_    924
#define T_    150
#define KD_   40
#define NSTEPS_ 10
#define BH    (B_ * H_)
#define LROWS 128            // batch rows per XCD
#define STRF  16             // ints between flags = 64B

__device__ __forceinline__ float sigmoidf_(float x) { return 1.f / (1.f + __expf(-x)); }
__device__ __forceinline__ float tanhf_(float x)    { return 1.f - 2.f / (__expf(2.f * x) + 1.f); }
__device__ __forceinline__ float b2f_(short s) {
    return __uint_as_float(((unsigned)(unsigned short)s) << 16);
}
__device__ __forceinline__ unsigned short f2bu_(float v) {
    union { __hip_bfloat16 b; unsigned short u; } cv;
    cv.b = __float2bfloat16(v);
    return cv.u;
}
// write-through (agent-scope) bf16 store: placement-independent correctness
__device__ __forceinline__ void stwt_(bf16* p, float v) {
    __hip_atomic_store((unsigned short*)p, f2bu_(v), __ATOMIC_RELAXED, __HIP_MEMORY_SCOPE_AGENT);
}

// ---------------------------------------------------------------------------
__global__ __launch_bounds__(256) void cvt_kernel(const float* __restrict__ src,
                                                  bf16* __restrict__ dst, int n) {
    int i = blockIdx.x * 256 + threadIdx.x;
    if (i < n) dst[i] = __float2bfloat16(src[i]);
}

__global__ void bias_kernel(const float* __restrict__ bih0, const float* __restrict__ bhh0,
                            const float* __restrict__ bih1, const float* __restrict__ bhh1,
                            float* __restrict__ b0, float* __restrict__ b1) {
    int i = blockIdx.x * 256 + threadIdx.x;
    if (i < G4H)      b0[i] = bih0[i] + bhh0[i];
    else if (i < 2*G4H) { int j = i - G4H; b1[j] = bih1[j] + bhh1[j]; }
}

// ---------------------------------------------------------------------------
__global__ __launch_bounds__(256) void conv_kernel(
    const float* __restrict__ x, const float* __restrict__ w,
    const float* __restrict__ cb, bf16* __restrict__ seq)
{
    __shared__ float w_lds[CIN_ * K_ * F_];
    __shared__ float x_lds[CIN_ * L_];
    int tid = threadIdx.x;
    int b = blockIdx.x;
    for (int i = tid; i < CIN_ * K_ * F_; i += 256) {
        int f = i & 31, r = i >> 5;
        w_lds[r * 32 + f] = w[f * (CIN_ * K_) + r];
    }
    const float* xb = x + (size_t)b * (CIN_ * L_);
    for (int i = tid; i < CIN_ * L_; i += 256)
        x_lds[i] = xb[i];
    __syncthreads();
    int f = tid & 31, tt = tid >> 5;
    float cbf = cb[f];
    for (int t0 = 0; t0 < T_; t0 += 8) {
        int t = t0 + tt;
        if (t < T_) {
            float acc = cbf;
            #pragma unroll
            for (int c = 0; c < CIN_; ++c) {
                const float* xr = x_lds + c * L_ + t * STRIDE_;
                const float* wr = w_lds + c * K_ * 32 + f;
                #pragma unroll
                for (int k = 0; k < K_; ++k)
                    acc += xr[k] * wr[k * 32];
            }
            acc = fmaxf(acc, 0.f);
            seq[(size_t)t * (B_ * F_) + b * F_ + f] = __float2bfloat16(acc);
        }
    }
}

// ---------------------------------------------------------------------------
// sync (r8-proven protocol, scoped to 16-peer XCD groups):
// release = barrier-drained write-through stores + waitcnt + agent flag store.
// acquire = relaxed poll (16 lanes for fa, 16 for fb) + buffer_inv.
// ---------------------------------------------------------------------------
__device__ __forceinline__ void wait2(const int* fa, int ta, const int* fb, int tb) {
    const int t = threadIdx.x;
    if (t < 64) {
        const int* p = nullptr; int tgt = 0;
        if (t < 16)               { if (fa) { p = fa + t * STRF;        tgt = ta; } }
        else if (t < 32)          { if (fb) { p = fb + (t - 16) * STRF; tgt = tb; } }
        for (;;) {
            int v = p ? __hip_atomic_load(p, __ATOMIC_RELAXED, __HIP_MEMORY_SCOPE_AGENT)
                      : 0x7fffffff;
            if (__all(v >= tgt)) break;
            __builtin_amdgcn_s_sleep(2);
        }
    }
    __syncthreads();
    __builtin_amdgcn_fence(__ATOMIC_ACQUIRE, "agent");   // buffer_inv
}

__device__ __forceinline__ void signal1(int* f, int val) {
    __syncthreads();                       // all waves' stores drained at barrier
    if (threadIdx.x == 0) {
        __builtin_amdgcn_s_waitcnt(0);     // own stores acked at coherent point
        __hip_atomic_store(f, val, __ATOMIC_RELAXED, __HIP_MEMORY_SCOPE_AGENT);
    }
}

// ---------------------------------------------------------------------------
// One layer step, XCD-local decomposition: this CU owns (m0: 128 local batch
// rows, 4 waves x 32 rows) x (j0: 32 h-cols -> 2 col-tiles x 4 gates).
// acc[mt][ctg] with ctg = g*2+ct. Whh slice LDS-resident (128KB); Wih either
// LDS (L0, 8KB) or read per-use from global/L2 (L1, frag addressing identical
// to the staging pattern). Rolled, compiler-scheduled (r8-proven best).
// Epilogue: r8's verified butterfly -> 8B write-through stores.
// ---------------------------------------------------------------------------
template<int P1KS, int XSTR, bool WG>
__device__ __forceinline__ void layer_step(
    const bf16* __restrict__ X, const bf16* __restrict__ Hprev,
    const short8* __restrict__ WldsH, const short8* __restrict__ WldsI,
    const bf16* __restrict__ WihG,
    const float (&bv)[4][2], float (&creg)[16], bf16* __restrict__ Hout,
    int m0, int j0, int wid, int lane)
{
    const int row16 = lane & 15;
    const int quad  = lane >> 4;
    const int mrow  = m0 + wid * 32 + row16;

    float4v acc[2][8];
    #pragma unroll
    for (int mt = 0; mt < 2; ++mt)
        #pragma unroll
        for (int c = 0; c < 8; ++c)
            acc[mt][c] = (float4v){0.f, 0.f, 0.f, 0.f};

    const bf16* wgb = WG ? (WihG + (size_t)(j0 + row16) * H_ + quad * 8) : nullptr;

    // part 1: X @ Wih^T
    for (int kg = 0; kg < P1KS; ++kg) {
        short8 av0 = *(const short8*)(X + (size_t)mrow * XSTR + kg * 32 + quad * 8);
        short8 av1 = *(const short8*)(X + (size_t)(mrow + 16) * XSTR + kg * 32 + quad * 8);
        #pragma unroll
        for (int ctg = 0; ctg < 8; ++ctg) {
            short8 bfr;
            if constexpr (WG) {
                const size_t off = ((size_t)(ctg >> 1) * 512 + (ctg & 1) * 16) * H_;
                bfr = *(const short8*)(wgb + off + kg * 32);
            } else {
                bfr = WldsI[(kg * 8 + ctg) * 64 + lane];
            }
            acc[0][ctg] = __builtin_amdgcn_mfma_f32_16x16x32_bf16(av0, bfr, acc[0][ctg], 0, 0, 0);
            acc[1][ctg] = __builtin_amdgcn_mfma_f32_16x16x32_bf16(av1, bfr, acc[1][ctg], 0, 0, 0);
        }
    }

    // part 2: Hprev @ Whh^T (B from LDS)
    for (int kg = 0; kg < 16; ++kg) {
        short8 av0 = *(const short8*)(Hprev + (size_t)mrow * H_ + kg * 32 + quad * 8);
        short8 av1 = *(const short8*)(Hprev + (size_t)(mrow + 16) * H_ + kg * 32 + quad * 8);
        #pragma unroll
        for (int ctg = 0; ctg < 8; ++ctg) {
            short8 bfr = WldsH[(kg * 8 + ctg) * 64 + lane];
            acc[0][ctg] = __builtin_amdgcn_mfma_f32_16x16x32_bf16(av0, bfr, acc[0][ctg], 0, 0, 0);
            acc[1][ctg] = __builtin_amdgcn_mfma_f32_16x16x32_bf16(av1, bfr, acc[1][ctg], 0, 0, 0);
        }
    }

    // ---- epilogue: gates, c update, packed h store ----
    float hval[16];
    #pragma unroll
    for (int mt = 0; mt < 2; ++mt) {
        #pragma unroll
        for (int ct = 0; ct < 2; ++ct) {
            #pragma unroll
            for (int rr = 0; rr < 4; ++rr) {
                int idx = (mt * 2 + ct) * 4 + rr;
                float ig = sigmoidf_(acc[mt][0 * 2 + ct][rr] + bv[0][ct]);
                float fg = sigmoidf_(acc[mt][1 * 2 + ct][rr] + bv[1][ct]);
                float gg = tanhf_(acc[mt][2 * 2 + ct][rr] + bv[2][ct]);
                float og = sigmoidf_(acc[mt][3 * 2 + ct][rr] + bv[3][ct]);
                float cn = fg * creg[idx] + ig * gg;
                creg[idx] = cn;
                hval[idx] = og * tanhf_(cn);
            }
        }
    }

    // butterfly pack (r8-verified): for fixed i, lanes l,l^1,l^2,l^3 hold the
    // same row at 4 adjacent cols -> 8B chunks; lane stores i with
    // (i>>2)==(lane&3); i = (mt*2+ct)*4+rr.
    unsigned wA[16];
    #pragma unroll
    for (int i = 0; i < 16; ++i) {
        float o = __shfl_xor(hval[i], 1);
        float lo = (lane & 1) ? o : hval[i];
        float hi = (lane & 1) ? hval[i] : o;
        wA[i] = (unsigned)f2bu_(lo) | ((unsigned)f2bu_(hi) << 16);
    }
    unsigned long long q[16];
    #pragma unroll
    for (int i = 0; i < 16; ++i) {
        unsigned o2 = __shfl_xor(wA[i], 2);
        q[i] = (lane & 2) ? (((unsigned long long)wA[i] << 32) | o2)
                          : (((unsigned long long)o2 << 32) | wA[i]);
    }
    #pragma unroll
    for (int i = 0; i < 16; ++i) {
        if ((i >> 2) == (lane & 3)) {
            int mt = i >> 3, ct = (i >> 2) & 1, rr = i & 3;
            int brow = m0 + wid * 32 + mt * 16 + quad * 4 + rr;
            int cch  = j0 + ct * 16 + (row16 & ~3);
            __hip_atomic_store((unsigned long long*)(Hout + (size_t)brow * H_ + cch), q[i],
                               __ATOMIC_RELAXED, __HIP_MEMORY_SCOPE_AGENT);
        }
    }
}

// ---------------------------------------------------------------------------
struct PP {
    const bf16 *seq, *Wih0, *Whh0, *Wih1, *Whh1, *dwb;
    const float *b0, *b1, *dec_b;
    float *fut;
    bf16 *h0, *h1, *y;       // h0/h1: 3 slots of [B,H] each
    int *flags;              // f0[8][16], f1[8][16], fy[8][16], 64B apart
};

// Persistent kernel, 256 blocks (1/CU), 256 threads. XCD-LOCAL DECOMPOSITION
// (round-10): xcd = bid&7 (hardware round-robins consecutive bids across the
// 8 XCDs), role = bid>>3. Each XCD owns batch rows [xcd*128, xcd*128+128) for
// the WHOLE network: roles 0-15 = L0 (h-cols role*32..+32, Whh0+Wih0 in LDS),
// roles 16-31 = L1 (Whh1 in LDS, Wih1 frags from L2). ALL data/flag
// dependencies are XCD-internal -> 8 independent 160-step chains, 16-peer
// sync groups, no global coupling. Protocol = r8's (write-through + agent
// flags + buffer_inv) so correctness never depends on actual placement.
// flag value = t+1 after step t. 3 h-slots (slot = t%3). Waits per XCD:
//   L0(t): f0>=t (peers' h0[t-1]), f1>=t-2 (h0 slot safety)
//   L1(t): f0>=t+1 (h0[t]), f1>=t (peers' h1[t-1] + slot safety)
//   y-round s: f1>=T+s (h1[T-1+s]), f0>=T+s for s>=1 (y slot consumed)
__global__ __launch_bounds__(256, 1) void lstm_persist(PP P) {
    __shared__ short8 WldsH[16 * 8 * 64];   // Whh slice, 128 KB
    __shared__ short8 WldsI[8 * 64];        // Wih0 slice, 8 KB (L0 only)

    const int bid   = blockIdx.x;
    const int xcd   = bid & 7;
    const int role  = bid >> 3;            // 0..31
    const bool isL0 = (role < 16);
    const int r     = isL0 ? role : role - 16;
    const int j0    = r * 32;
    const int m0    = xcd * LROWS;
    const int tid   = threadIdx.x;
    const int wid   = tid >> 6;
    const int lane  = tid & 63;
    const int row16 = lane & 15;

    // stage weight slices into LDS (frag-major; ctg = g*2+ct)
    {
        const bf16* Whh = isL0 ? P.Whh0 : P.Whh1;
        for (int i = 0; i < 32; ++i) {
            int s = tid + i * 256;
            int frag = s >> 6, ln = s & 63;
            int kg = frag >> 3, ctg = frag & 7;
            int g = ctg >> 1, ct = ctg & 1;
            WldsH[s] = *(const short8*)(Whh + (size_t)(g * 512 + j0 + ct * 16 + (ln & 15)) * H_
                                        + kg * 32 + (ln >> 4) * 8);
        }
        if (isL0) {
            for (int i = 0; i < 2; ++i) {
                int s = tid + i * 256;
                int ctg = s >> 6, ln = s & 63;
                int g = ctg >> 1, ct = ctg & 1;
                WldsI[s] = *(const short8*)(P.Wih0 + (size_t)(g * 512 + j0 + ct * 16 + (ln & 15)) * F_
                                            + (ln >> 4) * 8);
            }
        }
        __syncthreads();
    }

    // loop-invariant per-thread bias values: bv[g][ct]
    const float* bias = isL0 ? P.b0 : P.b1;
    float bv[4][2];
    #pragma unroll
    for (int g = 0; g < 4; ++g)
        #pragma unroll
        for (int ct = 0; ct < 2; ++ct)
            bv[g][ct] = bias[g * 512 + j0 + ct * 16 + row16];

    float creg[16];
    #pragma unroll
    for (int i = 0; i < 16; ++i) creg[i] = 0.f;

    int* f0 = P.flags;                   // [8][16]
    int* f1 = P.flags + 128 * STRF;
    int* fy = P.flags + 256 * STRF;
    int* f0x = f0 + xcd * 16 * STRF;
    int* f1x = f1 + xcd * 16 * STRF;
    int* fyx = fy + xcd * 16 * STRF;

    if (isL0) {
        // encoder t = 0..149
        for (int t = 0; t < T_; ++t) {
            wait2(f0x, t, f1x, t - 2);
            layer_step<1, 32, false>(P.seq + (size_t)t * B_ * F_,
                              P.h0 + (size_t)((t + 2) % 3) * BH, WldsH, WldsI, nullptr,
                              bv, creg, P.h0 + (size_t)(t % 3) * BH, m0, j0, wid, lane);
            signal1(f0x + r * STRF, t + 1);
        }
        // decoder: y-rounds interleaved with L0 steps
        for (int s = 0; s <= NSTEPS_; ++s) {
            wait2(f1x, T_ + s, (s >= 1) ? f0x : nullptr, T_ + s);
            {
                int id = r * 256 + tid;       // 0..4095 within XCD
                int lr = id >> 5, f = id & 31;
                int grow = m0 + lr;
                const short8* hv = (const short8*)(P.h1 + (size_t)((T_ - 1 + s) % 3) * BH
                                                   + (size_t)grow * H_);
                const short8* wv = (const short8*)(P.dwb + (size_t)f * H_);
                float acc = P.dec_b[f];
                for (int i = 0; i < H_ / 8; ++i) {
                    short8 h8 = hv[i], w8 = wv[i];
                    #pragma unroll
                    for (int k = 0; k < 8; ++k)
                        acc += b2f_(h8[k]) * b2f_(w8[k]);
                }
                stwt_(P.y + (size_t)grow * F_ + f, acc);
                if (s >= 1)
                    P.fut[(size_t)grow * (F_ * NSTEPS_) + f * NSTEPS_ + (s - 1)] = acc;
            }
            signal1(fyx + r * STRF, s + 1);
            if (s < NSTEPS_) {
                int t = T_ + s;
                wait2(f0x, t, f1x, t - 2);
                wait2(fyx, s + 1, nullptr, 0);
                layer_step<1, 32, false>(P.y,
                                  P.h0 + (size_t)((t + 2) % 3) * BH, WldsH, WldsI, nullptr,
                                  bv, creg, P.h0 + (size_t)(t % 3) * BH, m0, j0, wid, lane);
                signal1(f0x + r * STRF, t + 1);
            }
        }
    } else {
        // layer 1: t = 0..159
        for (int t = 0; t < T_ + NSTEPS_; ++t) {
            wait2(f0x, t + 1, f1x, t);
            layer_step<16, 512, true>(P.h0 + (size_t)(t % 3) * BH,
                                P.h1 + (size_t)((t + 2) % 3) * BH, WldsH, nullptr, P.Wih1,
                                bv, creg, P.h1 + (size_t)(t % 3) * BH, m0, j0, wid, lane);
            signal1(f1x + r * STRF, t + 1);
        }
    }
}

// ---------------------------------------------------------------------------
__global__ __launch_bounds__(256) void deconv_kernel(
    const float* __restrict__ fut, const float* __restrict__ dw,
    float* __restrict__ out)
{
    int idx = blockIdx.x * 256 + threadIdx.x;
    if (idx >= B_ * 49) return;
    int b = idx / 49, jj = idx % 49;
    int tlo = jj - (KD_ - 1); if (tlo < 0) tlo = 0;
    int thi = jj; if (thi > NSTEPS_ - 1) thi = NSTEPS_ - 1;
    float acc = 0.f;
    for (int f = 0; f < F_; ++f) {
        const float* fr = fut + (size_t)b * (F_ * NSTEPS_) + f * NSTEPS_;
        const float* wr = dw + f * KD_;
        for (int t = tlo; t <= thi; ++t)
            acc += fr[t] * wr[jj - t];
    }
    out[idx] = acc;
}

// ---------------------------------------------------------------------------
extern "C" void kernel_launch(void* const* d_in, const int* in_sizes, int n_in,
                              void* d_out, int out_size, void* d_ws, size_t ws_size,
                              hipStream_t stream) {
    const float* x       = (const float*)d_in[0];
    const float* conv_w  = (const float*)d_in[1];
    const float* conv_b  = (const float*)d_in[2];
    const float* Wih0f   = (const float*)d_in[3];
    const float* Whh0f   = (const float*)d_in[4];
    const float* bih0    = (const float*)d_in[5];
    const float* bhh0    = (const float*)d_in[6];
    const float* Wih1f   = (const float*)d_in[7];
    const float* Whh1f   = (const float*)d_in[8];
    const float* bih1    = (const float*)d_in[9];
    const float* bhh1    = (const float*)d_in[10];
    const float* dec_wf  = (const float*)d_in[11];
    const float* dec_b   = (const float*)d_in[12];
    const float* deconvw = (const float*)d_in[13];
    float* out = (float*)d_out;

    char* ws = (char*)d_ws;
    size_t off = 0;
    auto alloc = [&](size_t bytes) { char* p = ws + off; off = (off + bytes + 255) & ~(size_t)255; return p; };
    bf16*  seq   = (bf16*) alloc((size_t)T_ * B_ * F_ * 2);
    float* b0v   = (float*)alloc(G4H * 4);
    float* b1v   = (float*)alloc(G4H * 4);
    bf16*  h0    = (bf16*) alloc((size_t)3 * BH * 2);
    bf16*  h1    = (bf16*) alloc((size_t)3 * BH * 2);
    bf16*  y     = (bf16*) alloc((size_t)B_ * F_ * 2);
    float* fut   = (float*)alloc((size_t)B_ * F_ * NSTEPS_ * 4);
    bf16*  Wih0b = (bf16*) alloc((size_t)G4H * F_ * 2);
    bf16*  Whh0b = (bf16*) alloc((size_t)G4H * H_ * 2);
    bf16*  Wih1b = (bf16*) alloc((size_t)G4H * H_ * 2);
    bf16*  Whh1b = (bf16*) alloc((size_t)G4H * H_ * 2);
    bf16*  dec_wb= (bf16*) alloc((size_t)F_ * H_ * 2);
    int*   flags = (int*)  alloc(3 * 128 * STRF * 4);

    hipMemsetAsync(h0, 0, (size_t)3 * BH * 2, stream);
    hipMemsetAsync(h1, 0, (size_t)3 * BH * 2, stream);
    hipMemsetAsync(flags, 0, 3 * 128 * STRF * 4, stream);

    cvt_kernel<<<(G4H * F_ + 255) / 256, 256, 0, stream>>>(Wih0f, Wih0b, G4H * F_);
    cvt_kernel<<<(G4H * H_ + 255) / 256, 256, 0, stream>>>(Whh0f, Whh0b, G4H * H_);
    cvt_kernel<<<(G4H * H_ + 255) / 256, 256, 0, stream>>>(Wih1f, Wih1b, G4H * H_);
    cvt_kernel<<<(G4H * H_ + 255) / 256, 256, 0, stream>>>(Whh1f, Whh1b, G4H * H_);
    cvt_kernel<<<(F_ * H_ + 255) / 256, 256, 0, stream>>>(dec_wf, dec_wb, F_ * H_);

    bias_kernel<<<16, 256, 0, stream>>>(bih0, bhh0, bih1, bhh1, b0v, b1v);
    conv_kernel<<<B_, 256, 0, stream>>>(x, conv_w, conv_b, seq);

    PP P;
    P.seq = seq; P.Wih0 = Wih0b; P.Whh0 = Whh0b; P.Wih1 = Wih1b; P.Whh1 = Whh1b;
    P.dwb = dec_wb; P.b0 = b0v; P.b1 = b1v; P.dec_b = dec_b;
    P.fut = fut; P.h0 = h0; P.h1 = h1; P.y = y;
    P.flags = flags;

    void* args[] = { &P };
    hipError_t err = hipLaunchCooperativeKernel((const void*)lstm_persist,
                                                dim3(256), dim3(256), args, 0, stream);
    if (err != hipSuccess) {
        lstm_persist<<<256, 256, 0, stream>>>(P);
    }

    deconv_kernel<<<196, 256, 0, stream>>>(fut, deconvw, out);
}

// Round 11
// 5241.302 us; speedup vs baseline: 1.2358x; 1.2358x over previous
//
#include <hip/hip_runtime.h>
#include <hip/hip_bf16.h>

typedef __hip_bfloat16 bf16;
typedef __attribute__((ext_vector_type(8))) short short8;
typedef __attribute__((ext_vector_type(4))) float float4v;

#define B_    1024
#define H_    512
#define G4H   2048
#define F_    32
#define CIN_  4
#define K_    30
#define STRIDE_ 6
#define L_    924
#define T_    150
#define KD_   40
#define NSTEPS_ 10
#define BH    (B_ * H_)
#define STRF  16   // ints between flags = 64B (one cacheline per flag)

__device__ __forceinline__ float sigmoidf_(float x) { return 1.f / (1.f + __expf(-x)); }
__device__ __forceinline__ float tanhf_(float x)    { return 1.f - 2.f / (__expf(2.f * x) + 1.f); }
__device__ __forceinline__ float b2f_(short s) {
    return __uint_as_float(((unsigned)(unsigned short)s) << 16);
}
__device__ __forceinline__ unsigned short f2bu_(float v) {
    union { __hip_bfloat16 b; unsigned short u; } cv;
    cv.b = __float2bfloat16(v);
    return cv.u;
}
// write-through (agent-scope) bf16 store: no dirty L2 line -> no wbl2 needed
__device__ __forceinline__ void stwt_(bf16* p, float v) {
    __hip_atomic_store((unsigned short*)p, f2bu_(v), __ATOMIC_RELAXED, __HIP_MEMORY_SCOPE_AGENT);
}

// ---------------------------------------------------------------------------
__global__ __launch_bounds__(256) void cvt_kernel(const float* __restrict__ src,
                                                  bf16* __restrict__ dst, int n) {
    int i = blockIdx.x * 256 + threadIdx.x;
    if (i < n) dst[i] = __float2bfloat16(src[i]);
}

__global__ void bias_kernel(const float* __restrict__ bih0, const float* __restrict__ bhh0,
                            const float* __restrict__ bih1, const float* __restrict__ bhh1,
                            float* __restrict__ b0, float* __restrict__ b1) {
    int i = blockIdx.x * 256 + threadIdx.x;
    if (i < G4H)      b0[i] = bih0[i] + bhh0[i];
    else if (i < 2*G4H) { int j = i - G4H; b1[j] = bih1[j] + bhh1[j]; }
}

// ---------------------------------------------------------------------------
__global__ __launch_bounds__(256) void conv_kernel(
    const float* __restrict__ x, const float* __restrict__ w,
    const float* __restrict__ cb, bf16* __restrict__ seq)
{
    __shared__ float w_lds[CIN_ * K_ * F_];
    __shared__ float x_lds[CIN_ * L_];
    int tid = threadIdx.x;
    int b = blockIdx.x;
    for (int i = tid; i < CIN_ * K_ * F_; i += 256) {
        int f = i & 31, r = i >> 5;
        w_lds[r * 32 + f] = w[f * (CIN_ * K_) + r];
    }
    const float* xb = x + (size_t)b * (CIN_ * L_);
    for (int i = tid; i < CIN_ * L_; i += 256)
        x_lds[i] = xb[i];
    __syncthreads();
    int f = tid & 31, tt = tid >> 5;
    float cbf = cb[f];
    for (int t0 = 0; t0 < T_; t0 += 8) {
        int t = t0 + tt;
        if (t < T_) {
            float acc = cbf;
            #pragma unroll
            for (int c = 0; c < CIN_; ++c) {
                const float* xr = x_lds + c * L_ + t * STRIDE_;
                const float* wr = w_lds + c * K_ * 32 + f;
                #pragma unroll
                for (int k = 0; k < K_; ++k)
                    acc += xr[k] * wr[k * 32];
            }
            acc = fmaxf(acc, 0.f);
            seq[(size_t)t * (B_ * F_) + b * F_ + f] = __float2bfloat16(acc);
        }
    }
}

// ---------------------------------------------------------------------------
// sync (round-11 change: HOT-CLOCK BUSY POLL). Same protocol semantics as
// r8 (release = barrier-drained wt stores + waitcnt + agent flag store;
// acquire = poll + buffer_inv), but the poll now runs on ALL FOUR waves
// (redundant flag reads -- r9 proved poll traffic is irrelevant) and each
// poll iteration overlaps the flag-load RTT with a ~256-deep dependent FMA
// chain. Rationale: across 11 variants the per-link time was invariant at
// ~29-37us while VALUBusy sat at 12% -- consistent with DVFS dropping the
// clock on a chip that looks idle (waves s_sleeping / parked at barriers),
// stretching every latency in the serial chain. Keeping every SIMD issuing
// VALU ops during waits holds the clock up. No s_sleep.
// ---------------------------------------------------------------------------
__device__ __forceinline__ void wait2(const int* fa, int ta, const int* fb, int tb) {
    const int t = threadIdx.x & 63;        // all waves poll
    const int* p = nullptr; int tgt = 0;
    if (t < 32) { if (fa) { p = fa + t * STRF;        tgt = ta; } }
    else        { if (fb) { p = fb + (t - 32) * STRF; tgt = tb; } }
    float x = 1.f;
    for (;;) {
        int v = p ? __hip_atomic_load(p, __ATOMIC_RELAXED, __HIP_MEMORY_SCOPE_AGENT)
                  : 0x7fffffff;
        // dependent FMA chain issues while the flag load is in flight
        // (no data dep on v -> scheduler places it before the waitcnt).
        float y = x;
        #pragma unroll 16
        for (int i = 0; i < 256; ++i)
            y = __builtin_fmaf(y, 0.99997f, 1.0f);   // bounded fixed point
        x = y;
        if (__all(v >= tgt)) break;
    }
    asm volatile("" :: "v"(x));            // keep the spin alive
    __syncthreads();
    __builtin_amdgcn_fence(__ATOMIC_ACQUIRE, "agent");   // buffer_inv, no wbl2
}

__device__ __forceinline__ void signal1(int* f, int val) {
    __syncthreads();                       // all waves' stores drained at barrier
    if (threadIdx.x == 0) {
        __builtin_amdgcn_s_waitcnt(0);     // own stores acked at coherent point
        __hip_atomic_store(f, val, __ATOMIC_RELAXED, __HIP_MEMORY_SCOPE_AGENT);
    }
}

// ---------------------------------------------------------------------------
// One layer step for (m0: 256 rows) x (j0: 16 cols, 4 gates), 4 waves,
// 64 rows/wave. Wih AND Whh LDS-resident. C state in registers.
// Round-0 baseline inner loop (rolled, compiler-scheduled) + bias hoist +
// butterfly-packed 8B write-through h stores (r8-verified best structure).
// ---------------------------------------------------------------------------
template<int P1KS, int XSTR>
__device__ __forceinline__ void layer_step(
    const bf16* __restrict__ X, const bf16* __restrict__ Hprev,
    const short8* __restrict__ WldsH, const short8* __restrict__ WldsI,
    float bi, float bff, float bg, float bo,
    float (&creg)[16], bf16* __restrict__ Hout,
    int m0, int j0, int wid, int lane)
{
    const int row16 = lane & 15;
    const int quad  = lane >> 4;
    const int mrow  = m0 + wid * 64 + row16;

    float4v acc[4][4];
    #pragma unroll
    for (int ms = 0; ms < 4; ++ms)
        #pragma unroll
        for (int g = 0; g < 4; ++g)
            acc[ms][g] = (float4v){0.f, 0.f, 0.f, 0.f};

    // part 1: X @ Wih^T (B from LDS)
    for (int ks = 0; ks < P1KS; ++ks) {
        short8 av[4];
        #pragma unroll
        for (int ms = 0; ms < 4; ++ms)
            av[ms] = *(const short8*)(X + (size_t)(mrow + ms * 16) * XSTR
                                      + ks * 32 + quad * 8);
        #pragma unroll
        for (int g = 0; g < 4; ++g) {
            short8 bfr = WldsI[(ks * 4 + g) * 64 + lane];
            #pragma unroll
            for (int ms = 0; ms < 4; ++ms)
                acc[ms][g] = __builtin_amdgcn_mfma_f32_16x16x32_bf16(av[ms], bfr, acc[ms][g], 0, 0, 0);
        }
    }

    // part 2: Hprev @ Whh^T (B from LDS)
    for (int ks = 0; ks < 16; ++ks) {
        short8 av[4];
        #pragma unroll
        for (int ms = 0; ms < 4; ++ms)
            av[ms] = *(const short8*)(Hprev + (size_t)(mrow + ms * 16) * H_
                                      + ks * 32 + quad * 8);
        #pragma unroll
        for (int g = 0; g < 4; ++g) {
            short8 bfr = WldsH[(ks * 4 + g) * 64 + lane];
            #pragma unroll
            for (int ms = 0; ms < 4; ++ms)
                acc[ms][g] = __builtin_amdgcn_mfma_f32_16x16x32_bf16(av[ms], bfr, acc[ms][g], 0, 0, 0);
        }
    }

    // ---- epilogue: gates, c update, packed h store ----
    float hval[16];
    #pragma unroll
    for (int ms = 0; ms < 4; ++ms) {
        #pragma unroll
        for (int r = 0; r < 4; ++r) {
            float ig = sigmoidf_(acc[ms][0][r] + bi);
            float fg = sigmoidf_(acc[ms][1][r] + bff);
            float gg = tanhf_(acc[ms][2][r] + bg);
            float og = sigmoidf_(acc[ms][3][r] + bo);
            float cn = fg * creg[ms * 4 + r] + ig * gg;
            creg[ms * 4 + r] = cn;
            hval[ms * 4 + r] = og * tanhf_(cn);
        }
    }

    // butterfly pack: lanes l, l^1, l^2, l^3 hold the same row for a given
    // (ms,r) at 4 adjacent cols -> 8B chunks replicated in the 4-lane group,
    // each lane stores the 4 chunks with (i>>2) == (lane&3).
    unsigned wA[16];
    #pragma unroll
    for (int i = 0; i < 16; ++i) {
        float o = __shfl_xor(hval[i], 1);
        float lo = (lane & 1) ? o : hval[i];
        float hi = (lane & 1) ? hval[i] : o;
        wA[i] = (unsigned)f2bu_(lo) | ((unsigned)f2bu_(hi) << 16);
    }
    unsigned long long q[16];
    #pragma unroll
    for (int i = 0; i < 16; ++i) {
        unsigned o2 = __shfl_xor(wA[i], 2);
        q[i] = (lane & 2) ? (((unsigned long long)wA[i] << 32) | o2)
                          : (((unsigned long long)o2 << 32) | wA[i]);
    }
    const int cchunk = j0 + (row16 & ~3);
    #pragma unroll
    for (int i = 0; i < 16; ++i) {
        if ((i >> 2) == (lane & 3)) {
            int ms = i >> 2, r = i & 3;
            size_t off = (size_t)(m0 + wid * 64 + ms * 16 + quad * 4 + r) * H_ + cchunk;
            __hip_atomic_store((unsigned long long*)(Hout + off), q[i],
                               __ATOMIC_RELAXED, __HIP_MEMORY_SCOPE_AGENT);
        }
    }
}

// ---------------------------------------------------------------------------
struct PP {
    const bf16 *seq, *Wih0, *Whh0, *Wih1, *Whh1, *dwb;
    const float *b0, *b1, *dec_b;
    float *fut;
    bf16 *h0, *h1, *y;       // h0/h1: 3 slots of [B,H] each
    int *flags;              // f0[128], f1[128], fy[128], 64B apart
};

// Persistent kernel, 256 blocks (1/CU), 256 threads. Swizzle: bid = jj*8 +
// layer*4 + mg puts each (layer,mg) 32-block peer group (shares h-slice
// reads) on one XCD.
// flag value = t+1 after step t. 3 h-slots (slot = t%3). Waits:
//   L0(t): f0>=t   (peers' h0[t-1] ready + slot safety), f1>=t-2 (slot safety)
//   L1(t): f0>=t+1 (h0[t] ready), f1>=t (peers' h1[t-1] ready + slot safety)
//   y-round s: f1>=T+s (h1[T-1+s] ready), f0>=T+s for s>=1 (y slot consumed)
__global__ __launch_bounds__(256, 1) void lstm_persist(PP P) {
    __shared__ short8 WldsH[4096];   // Whh slice, 64 KB
    __shared__ short8 WldsI[4096];   // Wih slice, 64 KB (L0 uses 256 entries)

    const int bid   = blockIdx.x;
    const int gsw   = bid & 7;
    const bool isL0 = (gsw < 4);
    const int mg    = gsw & 3;
    const int jj    = bid >> 3;
    const int lb    = mg * 32 + jj;       // logical id within layer
    const int j0    = jj * 16;
    const int m0    = mg * 256;
    const int tid   = threadIdx.x;
    const int wid   = tid >> 6;
    const int lane  = tid & 63;

    // stage weight slices into LDS (frag-major)
    {
        const bf16* Whh = isL0 ? P.Whh0 : P.Whh1;
        for (int i = 0; i < 16; ++i) {
            int s = tid + i * 256;
            int frag = s >> 6, ln = s & 63;
            int ks = frag >> 2, g = frag & 3;
            WldsH[s] = *(const short8*)(Whh + (size_t)(g * H_ + j0 + (ln & 15)) * H_
                                        + ks * 32 + (ln >> 4) * 8);
        }
        if (isL0) {
            int frag = tid >> 6, ln = tid & 63;
            int g = frag & 3;   // ks = 0
            WldsI[tid] = *(const short8*)(P.Wih0 + (size_t)(g * H_ + j0 + (ln & 15)) * F_
                                          + (ln >> 4) * 8);
        } else {
            for (int i = 0; i < 16; ++i) {
                int s = tid + i * 256;
                int frag = s >> 6, ln = s & 63;
                int ks = frag >> 2, g = frag & 3;
                WldsI[s] = *(const short8*)(P.Wih1 + (size_t)(g * H_ + j0 + (ln & 15)) * H_
                                            + ks * 32 + (ln >> 4) * 8);
            }
        }
        __syncthreads();
    }

    // loop-invariant per-thread bias values (hoisted, r3+)
    const float* bias = isL0 ? P.b0 : P.b1;
    const int jb  = j0 + (lane & 15);
    const float bi  = bias[jb];
    const float bff = bias[H_ + jb];
    const float bg  = bias[2 * H_ + jb];
    const float bo  = bias[3 * H_ + jb];

    float creg[16];
    #pragma unroll
    for (int i = 0; i < 16; ++i) creg[i] = 0.f;

    int* f0 = P.flags;
    int* f1 = P.flags + 128 * STRF;
    int* fy = P.flags + 256 * STRF;
    const int* f0g = f0 + mg * 32 * STRF;
    const int* f1g = f1 + mg * 32 * STRF;
    const int* fyg = fy + mg * 32 * STRF;

    if (isL0) {
        // encoder t = 0..149
        for (int t = 0; t < T_; ++t) {
            wait2(f0g, t, f1g, t - 2);
            layer_step<1, 32>(P.seq + (size_t)t * B_ * F_,
                              P.h0 + (size_t)((t + 2) % 3) * BH, WldsH, WldsI,
                              bi, bff, bg, bo,
                              creg, P.h0 + (size_t)(t % 3) * BH, m0, j0, wid, lane);
            signal1(f0 + lb * STRF, t + 1);
        }
        // decoder: y-rounds interleaved with L0 steps
        for (int s = 0; s <= NSTEPS_; ++s) {
            wait2(f1g, T_ + s, (s >= 1) ? f0g : nullptr, T_ + s);
            {
                int id = lb * 256 + tid;        // b*32 + f
                int br = id >> 5, f = id & 31;
                const short8* hv = (const short8*)(P.h1 + (size_t)((T_ - 1 + s) % 3) * BH
                                                   + (size_t)br * H_);
                const short8* wv = (const short8*)(P.dwb + (size_t)f * H_);
                float acc = P.dec_b[f];
                for (int i = 0; i < H_ / 8; ++i) {
                    short8 h8 = hv[i], w8 = wv[i];
                    #pragma unroll
                    for (int k = 0; k < 8; ++k)
                        acc += b2f_(h8[k]) * b2f_(w8[k]);
                }
                stwt_(P.y + id, acc);
                if (s >= 1)
                    P.fut[(size_t)br * (F_ * NSTEPS_) + f * NSTEPS_ + (s - 1)] = acc;
            }
            signal1(fy + lb * STRF, s + 1);
            if (s < NSTEPS_) {
                int t = T_ + s;
                wait2(f0g, t, f1g, t - 2);
                wait2(fyg, s + 1, nullptr, 0);
                layer_step<1, 32>(P.y,
                                  P.h0 + (size_t)((t + 2) % 3) * BH, WldsH, WldsI,
                                  bi, bff, bg, bo,
                                  creg, P.h0 + (size_t)(t % 3) * BH, m0, j0, wid, lane);
                signal1(f0 + lb * STRF, t + 1);
            }
        }
    } else {
        // layer 1: t = 0..159
        for (int t = 0; t < T_ + NSTEPS_; ++t) {
            wait2(f0g, t + 1, f1g, t);
            layer_step<16, 512>(P.h0 + (size_t)(t % 3) * BH,
                                P.h1 + (size_t)((t + 2) % 3) * BH, WldsH, WldsI,
                                bi, bff, bg, bo,
                                creg, P.h1 + (size_t)(t % 3) * BH, m0, j0, wid, lane);
            signal1(f1 + lb * STRF, t + 1);
        }
    }
}

// ---------------------------------------------------------------------------
__global__ __launch_bounds__(256) void deconv_kernel(
    const float* __restrict__ fut, const float* __restrict__ dw,
    float* __restrict__ out)
{
    int idx = blockIdx.x * 256 + threadIdx.x;
    if (idx >= B_ * 49) return;
    int b = idx / 49, jj = idx % 49;
    int tlo = jj - (KD_ - 1); if (tlo < 0) tlo = 0;
    int thi = jj; if (thi > NSTEPS_ - 1) thi = NSTEPS_ - 1;
    float acc = 0.f;
    for (int f = 0; f < F_; ++f) {
        const float* fr = fut + (size_t)b * (F_ * NSTEPS_) + f * NSTEPS_;
        const float* wr = dw + f * KD_;
        for (int t = tlo; t <= thi; ++t)
            acc += fr[t] * wr[jj - t];
    }
    out[idx] = acc;
}

// ---------------------------------------------------------------------------
extern "C" void kernel_launch(void* const* d_in, const int* in_sizes, int n_in,
                              void* d_out, int out_size, void* d_ws, size_t ws_size,
                              hipStream_t stream) {
    const float* x       = (const float*)d_in[0];
    const float* conv_w  = (const float*)d_in[1];
    const float* conv_b  = (const float*)d_in[2];
    const float* Wih0f   = (const float*)d_in[3];
    const float* Whh0f   = (const float*)d_in[4];
    const float* bih0    = (const float*)d_in[5];
    const float* bhh0    = (const float*)d_in[6];
    const float* Wih1f   = (const float*)d_in[7];
    const float* Whh1f   = (const float*)d_in[8];
    const float* bih1    = (const float*)d_in[9];
    const float* bhh1    = (const float*)d_in[10];
    const float* dec_wf  = (const float*)d_in[11];
    const float* dec_b   = (const float*)d_in[12];
    const float* deconvw = (const float*)d_in[13];
    float* out = (float*)d_out;

    char* ws = (char*)d_ws;
    size_t off = 0;
    auto alloc = [&](size_t bytes) { char* p = ws + off; off = (off + bytes + 255) & ~(size_t)255; return p; };
    bf16*  seq   = (bf16*) alloc((size_t)T_ * B_ * F_ * 2);
    float* b0v   = (float*)alloc(G4H * 4);
    float* b1v   = (float*)alloc(G4H * 4);
    bf16*  h0    = (bf16*) alloc((size_t)3 * BH * 2);
    bf16*  h1    = (bf16*) alloc((size_t)3 * BH * 2);
    bf16*  y     = (bf16*) alloc((size_t)B_ * F_ * 2);
    float* fut   = (float*)alloc((size_t)B_ * F_ * NSTEPS_ * 4);
    bf16*  Wih0b = (bf16*) alloc((size_t)G4H * F_ * 2);
    bf16*  Whh0b = (bf16*) alloc((size_t)G4H * H_ * 2);
    bf16*  Wih1b = (bf16*) alloc((size_t)G4H * H_ * 2);
    bf16*  Whh1b = (bf16*) alloc((size_t)G4H * H_ * 2);
    bf16*  dec_wb= (bf16*) alloc((size_t)F_ * H_ * 2);
    int*   flags = (int*)  alloc(3 * 128 * STRF * 4);

    hipMemsetAsync(h0, 0, (size_t)3 * BH * 2, stream);
    hipMemsetAsync(h1, 0, (size_t)3 * BH * 2, stream);
    hipMemsetAsync(flags, 0, 3 * 128 * STRF * 4, stream);

    cvt_kernel<<<(G4H * F_ + 255) / 256, 256, 0, stream>>>(Wih0f, Wih0b, G4H * F_);
    cvt_kernel<<<(G4H * H_ + 255) / 256, 256, 0, stream>>>(Whh0f, Whh0b, G4H * H_);
    cvt_kernel<<<(G4H * H_ + 255) / 256, 256, 0, stream>>>(Wih1f, Wih1b, G4H * H_);
    cvt_kernel<<<(G4H * H_ + 255) / 256, 256, 0, stream>>>(Whh1f, Whh1b, G4H * H_);
    cvt_kernel<<<(F_ * H_ + 255) / 256, 256, 0, stream>>>(dec_wf, dec_wb, F_ * H_);

    bias_kernel<<<16, 256, 0, stream>>>(bih0, bhh0, bih1, bhh1, b0v, b1v);
    conv_kernel<<<B_, 256, 0, stream>>>(x, conv_w, conv_b, seq);

    PP P;
    P.seq = seq; P.Wih0 = Wih0b; P.Whh0 = Whh0b; P.Wih1 = Wih1b; P.Whh1 = Whh1b;
    P.dwb = dec_wb; P.b0 = b0v; P.b1 = b1v; P.dec_b = dec_b;
    P.fut = fut; P.h0 = h0; P.h1 = h1; P.y = y;
    P.flags = flags;

    void* args[] = { &P };
    hipError_t err = hipLaunchCooperativeKernel((const void*)lstm_persist,
                                                dim3(256), dim3(256), args, 0, stream);
    if (err != hipSuccess) {
        lstm_persist<<<256, 256, 0, stream>>>(P);
    }

    deconv_kernel<<<196, 256, 0, stream>>>(fut, deconvw, out);
}

// Round 12
// 4967.821 us; speedup vs baseline: 1.3038x; 1.0551x over previous
//
#include <hip/hip_runtime.h>
#include <hip/hip_bf16.h>

typedef __hip_bfloat16 bf16;
typedef __attribute__((ext_vector_type(8))) short short8;
typedef __attribute__((ext_vector_type(4))) float float4v;

#define B_    1024
#define H_    512
#define G4H   2048
#define F_    32
#define CIN_  4
#define K_    30
#define STRIDE_ 6
#define L_    924
#define T_    150
#define KD_   40
#define NSTEPS_ 10
#define BH    (B_ * H_)
#define STRF  16   // ints between flags = 64B (one cacheline per flag)

__device__ __forceinline__ float sigmoidf_(float x) { return 1.f / (1.f + __expf(-x)); }
__device__ __forceinline__ float tanhf_(float x)    { return 1.f - 2.f / (__expf(2.f * x) + 1.f); }
__device__ __forceinline__ float b2f_(short s) {
    return __uint_as_float(((unsigned)(unsigned short)s) << 16);
}
__device__ __forceinline__ unsigned short f2bu_(float v) {
    union { __hip_bfloat16 b; unsigned short u; } cv;
    cv.b = __float2bfloat16(v);
    return cv.u;
}

// ---------------------------------------------------------------------------
__global__ __launch_bounds__(256) void cvt_kernel(const float* __restrict__ src,
                                                  bf16* __restrict__ dst, int n) {
    int i = blockIdx.x * 256 + threadIdx.x;
    if (i < n) dst[i] = __float2bfloat16(src[i]);
}

__global__ void bias_kernel(const float* __restrict__ bih0, const float* __restrict__ bhh0,
                            const float* __restrict__ bih1, const float* __restrict__ bhh1,
                            float* __restrict__ b0, float* __restrict__ b1) {
    int i = blockIdx.x * 256 + threadIdx.x;
    if (i < G4H)      b0[i] = bih0[i] + bhh0[i];
    else if (i < 2*G4H) { int j = i - G4H; b1[j] = bih1[j] + bhh1[j]; }
}

// ---------------------------------------------------------------------------
__global__ __launch_bounds__(256) void conv_kernel(
    const float* __restrict__ x, const float* __restrict__ w,
    const float* __restrict__ cb, bf16* __restrict__ seq)
{
    __shared__ float w_lds[CIN_ * K_ * F_];
    __shared__ float x_lds[CIN_ * L_];
    int tid = threadIdx.x;
    int b = blockIdx.x;
    for (int i = tid; i < CIN_ * K_ * F_; i += 256) {
        int f = i & 31, r = i >> 5;
        w_lds[r * 32 + f] = w[f * (CIN_ * K_) + r];
    }
    const float* xb = x + (size_t)b * (CIN_ * L_);
    for (int i = tid; i < CIN_ * L_; i += 256)
        x_lds[i] = xb[i];
    __syncthreads();
    int f = tid & 31, tt = tid >> 5;
    float cbf = cb[f];
    for (int t0 = 0; t0 < T_; t0 += 8) {
        int t = t0 + tt;
        if (t < T_) {
            float acc = cbf;
            #pragma unroll
            for (int c = 0; c < CIN_; ++c) {
                const float* xr = x_lds + c * L_ + t * STRIDE_;
                const float* wr = w_lds + c * K_ * 32 + f;
                #pragma unroll
                for (int k = 0; k < K_; ++k)
                    acc += xr[k] * wr[k * 32];
            }
            acc = fmaxf(acc, 0.f);
            seq[(size_t)t * (B_ * F_) + b * F_ + f] = __float2bfloat16(acc);
        }
    }
}

// ---------------------------------------------------------------------------
// sync, SPLIT FAST/SLOW PROTOCOL (round-12 change).
// Observation: in all 12 prior variants, the critical-path link contained a
// write-through store drain to the L3 coherence point before the signal
// (signal1's barrier drains every wave's WT stores). That drain is the one
// component never isolated. Here:
//   fast flag  = fires after PLAIN stores drain (L2-ack). Carries the
//                same-XCD chains (L0->L0 peers, L1->L1 peers; r5-verified
//                that same-XCD plain-store handoff + buffer_inv is correct).
//   slow flag  = published at the NEXT step's entry, where that step's
//                entry barrier has (for free) drained the WT stores issued
//                after the previous fast signal. Carries cross-XCD data
//                edges (h0->L1, h1->decoder). Signal-then-wait order at
//                every step entry keeps the dependency graph acyclic.
// Wait VALUES identical to the 12x-verified protocol; only which flag
// variant carries each edge changes.
// ---------------------------------------------------------------------------
__device__ __forceinline__ void wait2(const int* fa, int ta, const int* fb, int tb) {
    const int t = threadIdx.x;
    if (t < 64) {
        const int* p = nullptr; int tgt = 0;
        if (t < 32) { if (fa) { p = fa + t * STRF;        tgt = ta; } }
        else        { if (fb) { p = fb + (t - 32) * STRF; tgt = tb; } }
        for (;;) {
            int v = p ? __hip_atomic_load(p, __ATOMIC_RELAXED, __HIP_MEMORY_SCOPE_AGENT)
                      : 0x7fffffff;
            if (__all(v >= tgt)) break;
            __builtin_amdgcn_s_sleep(2);
        }
    }
    __syncthreads();
    __builtin_amdgcn_fence(__ATOMIC_ACQUIRE, "agent");   // buffer_inv
}

// fast release: plain stores drained at barrier (L2-ack), then flag.
__device__ __forceinline__ void signal1(int* f, int val) {
    __syncthreads();
    if (threadIdx.x == 0) {
        __builtin_amdgcn_s_waitcnt(0);
        __hip_atomic_store(f, val, __ATOMIC_RELAXED, __HIP_MEMORY_SCOPE_AGENT);
    }
}

// slow release: barrier drains the WT stores issued since the last barrier
// (they have had a whole step to complete -> near-zero residual wait).
__device__ __forceinline__ void signal_slow(int* f, int val) {
    __syncthreads();
    if (threadIdx.x == 0) {
        __builtin_amdgcn_s_waitcnt(0);
        __hip_atomic_store(f, val, __ATOMIC_RELAXED, __HIP_MEMORY_SCOPE_AGENT);
    }
}

// cross-XCD WT copy of this lane's 4 h-chunks (issued AFTER the fast signal;
// drained by the next entry barrier).
__device__ __forceinline__ void wt_stores(bf16* Hwt, const unsigned long long (&qv)[4],
                                          int m0, int j0, int wid, int lane) {
    const int row16 = lane & 15, quad = lane >> 4, ms = lane & 3;
    const int cchunk = j0 + (row16 & ~3);
    #pragma unroll
    for (int r = 0; r < 4; ++r) {
        size_t off = (size_t)(m0 + wid * 64 + ms * 16 + quad * 4 + r) * H_ + cchunk;
        __hip_atomic_store((unsigned long long*)(Hwt + off), qv[r],
                           __ATOMIC_RELAXED, __HIP_MEMORY_SCOPE_AGENT);
    }
}

// ---------------------------------------------------------------------------
// One layer step for (m0: 256 rows) x (j0: 16 cols, 4 gates), 4 waves,
// 64 rows/wave. Wih AND Whh LDS-resident. C state in registers.
// r8 structure (rolled loops, bias hoist, butterfly pack) except the h
// stores are now PLAIN cached (fast drain); the lane's 4 packed chunks are
// returned in qout for the caller's deferred WT copy.
// ---------------------------------------------------------------------------
template<int P1KS, int XSTR>
__device__ __forceinline__ void layer_step(
    const bf16* __restrict__ X, const bf16* __restrict__ Hprev,
    const short8* __restrict__ WldsH, const short8* __restrict__ WldsI,
    float bi, float bff, float bg, float bo,
    float (&creg)[16], bf16* __restrict__ Hout, unsigned long long (&qout)[4],
    int m0, int j0, int wid, int lane)
{
    const int row16 = lane & 15;
    const int quad  = lane >> 4;
    const int mrow  = m0 + wid * 64 + row16;

    float4v acc[4][4];
    #pragma unroll
    for (int ms = 0; ms < 4; ++ms)
        #pragma unroll
        for (int g = 0; g < 4; ++g)
            acc[ms][g] = (float4v){0.f, 0.f, 0.f, 0.f};

    // part 1: X @ Wih^T (B from LDS)
    for (int ks = 0; ks < P1KS; ++ks) {
        short8 av[4];
        #pragma unroll
        for (int ms = 0; ms < 4; ++ms)
            av[ms] = *(const short8*)(X + (size_t)(mrow + ms * 16) * XSTR
                                      + ks * 32 + quad * 8);
        #pragma unroll
        for (int g = 0; g < 4; ++g) {
            short8 bfr = WldsI[(ks * 4 + g) * 64 + lane];
            #pragma unroll
            for (int ms = 0; ms < 4; ++ms)
                acc[ms][g] = __builtin_amdgcn_mfma_f32_16x16x32_bf16(av[ms], bfr, acc[ms][g], 0, 0, 0);
        }
    }

    // part 2: Hprev @ Whh^T (B from LDS)
    for (int ks = 0; ks < 16; ++ks) {
        short8 av[4];
        #pragma unroll
        for (int ms = 0; ms < 4; ++ms)
            av[ms] = *(const short8*)(Hprev + (size_t)(mrow + ms * 16) * H_
                                      + ks * 32 + quad * 8);
        #pragma unroll
        for (int g = 0; g < 4; ++g) {
            short8 bfr = WldsH[(ks * 4 + g) * 64 + lane];
            #pragma unroll
            for (int ms = 0; ms < 4; ++ms)
                acc[ms][g] = __builtin_amdgcn_mfma_f32_16x16x32_bf16(av[ms], bfr, acc[ms][g], 0, 0, 0);
        }
    }

    // ---- epilogue: gates, c update, packed plain h store ----
    float hval[16];
    #pragma unroll
    for (int ms = 0; ms < 4; ++ms) {
        #pragma unroll
        for (int r = 0; r < 4; ++r) {
            float ig = sigmoidf_(acc[ms][0][r] + bi);
            float fg = sigmoidf_(acc[ms][1][r] + bff);
            float gg = tanhf_(acc[ms][2][r] + bg);
            float og = sigmoidf_(acc[ms][3][r] + bo);
            float cn = fg * creg[ms * 4 + r] + ig * gg;
            creg[ms * 4 + r] = cn;
            hval[ms * 4 + r] = og * tanhf_(cn);
        }
    }

    unsigned wA[16];
    #pragma unroll
    for (int i = 0; i < 16; ++i) {
        float o = __shfl_xor(hval[i], 1);
        float lo = (lane & 1) ? o : hval[i];
        float hi = (lane & 1) ? hval[i] : o;
        wA[i] = (unsigned)f2bu_(lo) | ((unsigned)f2bu_(hi) << 16);
    }
    unsigned long long q[16];
    #pragma unroll
    for (int i = 0; i < 16; ++i) {
        unsigned o2 = __shfl_xor(wA[i], 2);
        q[i] = (lane & 2) ? (((unsigned long long)wA[i] << 32) | o2)
                          : (((unsigned long long)o2 << 32) | wA[i]);
    }
    const int cchunk = j0 + (row16 & ~3);
    #pragma unroll
    for (int i = 0; i < 16; ++i) {
        if ((i >> 2) == (lane & 3)) {
            int ms = i >> 2, r = i & 3;
            size_t off = (size_t)(m0 + wid * 64 + ms * 16 + quad * 4 + r) * H_ + cchunk;
            *(unsigned long long*)(Hout + off) = q[i];   // plain cached store
            qout[i & 3] = q[i];
        }
    }
}

// ---------------------------------------------------------------------------
struct PP {
    const bf16 *seq, *Wih0, *Whh0, *Wih1, *Whh1, *dwb;
    const float *b0, *b1, *dec_b;
    float *fut;
    bf16 *h0, *h1, *y;       // h0/h1: 3 slots of [B,H] each
    int *flags;              // f0f, f1f, fy, f0s, f1s: 5 x 128 flags, 64B apart
};

// Persistent kernel, 256 blocks (1/CU), 256 threads. Swizzle: bid = jj*8 +
// layer*4 + mg puts each (layer,mg) 32-block peer group on one XCD, so the
// within-layer chains run on same-XCD plain-store handoff (fast links).
// Cross-XCD edges (h0->L1 always; h1->y-rounds) ride the slow flags.
// flag value = t+1 after step t (fast) / t = "steps <t WT-visible" (slow).
// Waits (values identical to the verified r8 protocol):
//   L0(t): f0f>=t, f1f>=t-2        L1(t): f0s>=t+1, f1f>=t
//   y-round s: f1s>=T+s, f0f>=T+s (s>=1); L0 dec t: f0f>=t, f1f>=t-2, fy>=s+1
__global__ __launch_bounds__(256, 1) void lstm_persist(PP P) {
    __shared__ short8 WldsH[4096];   // Whh slice, 64 KB
    __shared__ short8 WldsI[4096];   // Wih slice, 64 KB (L0 uses 256 entries)

    const int bid   = blockIdx.x;
    const int gsw   = bid & 7;
    const bool isL0 = (gsw < 4);
    const int mg    = gsw & 3;
    const int jj    = bid >> 3;
    const int lb    = mg * 32 + jj;       // logical id within layer
    const int j0    = jj * 16;
    const int m0    = mg * 256;
    const int tid   = threadIdx.x;
    const int wid   = tid >> 6;
    const int lane  = tid & 63;

    // stage weight slices into LDS (frag-major)
    {
        const bf16* Whh = isL0 ? P.Whh0 : P.Whh1;
        for (int i = 0; i < 16; ++i) {
            int s = tid + i * 256;
            int frag = s >> 6, ln = s & 63;
            int ks = frag >> 2, g = frag & 3;
            WldsH[s] = *(const short8*)(Whh + (size_t)(g * H_ + j0 + (ln & 15)) * H_
                                        + ks * 32 + (ln >> 4) * 8);
        }
        if (isL0) {
            int frag = tid >> 6, ln = tid & 63;
            int g = frag & 3;   // ks = 0
            WldsI[tid] = *(const short8*)(P.Wih0 + (size_t)(g * H_ + j0 + (ln & 15)) * F_
                                          + (ln >> 4) * 8);
        } else {
            for (int i = 0; i < 16; ++i) {
                int s = tid + i * 256;
                int frag = s >> 6, ln = s & 63;
                int ks = frag >> 2, g = frag & 3;
                WldsI[s] = *(const short8*)(P.Wih1 + (size_t)(g * H_ + j0 + (ln & 15)) * H_
                                            + ks * 32 + (ln >> 4) * 8);
            }
        }
        __syncthreads();
    }

    // loop-invariant per-thread bias values
    const float* bias = isL0 ? P.b0 : P.b1;
    const int jb  = j0 + (lane & 15);
    const float bi  = bias[jb];
    const float bff = bias[H_ + jb];
    const float bg  = bias[2 * H_ + jb];
    const float bo  = bias[3 * H_ + jb];

    float creg[16];
    #pragma unroll
    for (int i = 0; i < 16; ++i) creg[i] = 0.f;

    int* f0f = P.flags;
    int* f1f = P.flags + 128 * STRF;
    int* fy  = P.flags + 256 * STRF;
    int* f0s = P.flags + 384 * STRF;
    int* f1s = P.flags + 512 * STRF;
    const int* f0fg = f0f + mg * 32 * STRF;
    const int* f1fg = f1f + mg * 32 * STRF;
    const int* fyg  = fy  + mg * 32 * STRF;
    const int* f0sg = f0s + mg * 32 * STRF;
    const int* f1sg = f1s + mg * 32 * STRF;

    if (isL0) {
        // encoder t = 0..149
        for (int t = 0; t < T_; ++t) {
            signal_slow(f0s + lb * STRF, t);         // prev step's WT now drained
            wait2(f0fg, t, f1fg, t - 2);
            unsigned long long qv[4];
            layer_step<1, 32>(P.seq + (size_t)t * B_ * F_,
                              P.h0 + (size_t)((t + 2) % 3) * BH, WldsH, WldsI,
                              bi, bff, bg, bo,
                              creg, P.h0 + (size_t)(t % 3) * BH, qv, m0, j0, wid, lane);
            signal1(f0f + lb * STRF, t + 1);         // fast: plain stores visible
            wt_stores(P.h0 + (size_t)(t % 3) * BH, qv, m0, j0, wid, lane);
        }
        // decoder: y-rounds interleaved with L0 steps
        for (int s = 0; s <= NSTEPS_; ++s) {
            signal_slow(f0s + lb * STRF, T_ + s);    // drains decoder L0 WT too
            wait2(f1sg, T_ + s, (s >= 1) ? f0fg : nullptr, T_ + s);
            {
                int id = lb * 256 + tid;        // b*32 + f
                int br = id >> 5, f = id & 31;
                const short8* hv = (const short8*)(P.h1 + (size_t)((T_ - 1 + s) % 3) * BH
                                                   + (size_t)br * H_);
                const short8* wv = (const short8*)(P.dwb + (size_t)f * H_);
                float acc = P.dec_b[f];
                for (int i = 0; i < H_ / 8; ++i) {
                    short8 h8 = hv[i], w8 = wv[i];
                    #pragma unroll
                    for (int k = 0; k < 8; ++k)
                        acc += b2f_(h8[k]) * b2f_(w8[k]);
                }
                P.y[id] = __float2bfloat16(acc);     // plain: consumers same-XCD
                if (s >= 1)
                    P.fut[(size_t)br * (F_ * NSTEPS_) + f * NSTEPS_ + (s - 1)] = acc;
            }
            signal1(fy + lb * STRF, s + 1);
            if (s < NSTEPS_) {
                int t = T_ + s;
                wait2(f0fg, t, f1fg, t - 2);
                wait2(fyg, s + 1, nullptr, 0);
                unsigned long long qv[4];
                layer_step<1, 32>(P.y,
                                  P.h0 + (size_t)((t + 2) % 3) * BH, WldsH, WldsI,
                                  bi, bff, bg, bo,
                                  creg, P.h0 + (size_t)(t % 3) * BH, qv, m0, j0, wid, lane);
                signal1(f0f + lb * STRF, t + 1);
                wt_stores(P.h0 + (size_t)(t % 3) * BH, qv, m0, j0, wid, lane);
            }
        }
    } else {
        // layer 1: t = 0..159
        for (int t = 0; t < T_ + NSTEPS_; ++t) {
            signal_slow(f1s + lb * STRF, t);         // prev step's WT (if any) drained
            wait2(f0sg, t + 1, f1fg, t);
            unsigned long long qv[4];
            layer_step<16, 512>(P.h0 + (size_t)(t % 3) * BH,
                                P.h1 + (size_t)((t + 2) % 3) * BH, WldsH, WldsI,
                                bi, bff, bg, bo,
                                creg, P.h1 + (size_t)(t % 3) * BH, qv, m0, j0, wid, lane);
            signal1(f1f + lb * STRF, t + 1);
            if (t >= T_ - 1)                         // decoder-visible steps only
                wt_stores(P.h1 + (size_t)(t % 3) * BH, qv, m0, j0, wid, lane);
        }
        signal_slow(f1s + lb * STRF, T_ + NSTEPS_);  // final y-round dependency
    }
}

// ---------------------------------------------------------------------------
__global__ __launch_bounds__(256) void deconv_kernel(
    const float* __restrict__ fut, const float* __restrict__ dw,
    float* __restrict__ out)
{
    int idx = blockIdx.x * 256 + threadIdx.x;
    if (idx >= B_ * 49) return;
    int b = idx / 49, jj = idx % 49;
    int tlo = jj - (KD_ - 1); if (tlo < 0) tlo = 0;
    int thi = jj; if (thi > NSTEPS_ - 1) thi = NSTEPS_ - 1;
    float acc = 0.f;
    for (int f = 0; f < F_; ++f) {
        const float* fr = fut + (size_t)b * (F_ * NSTEPS_) + f * NSTEPS_;
        const float* wr = dw + f * KD_;
        for (int t = tlo; t <= thi; ++t)
            acc += fr[t] * wr[jj - t];
    }
    out[idx] = acc;
}

// ---------------------------------------------------------------------------
extern "C" void kernel_launch(void* const* d_in, const int* in_sizes, int n_in,
                              void* d_out, int out_size, void* d_ws, size_t ws_size,
                              hipStream_t stream) {
    const float* x       = (const float*)d_in[0];
    const float* conv_w  = (const float*)d_in[1];
    const float* conv_b  = (const float*)d_in[2];
    const float* Wih0f   = (const float*)d_in[3];
    const float* Whh0f   = (const float*)d_in[4];
    const float* bih0    = (const float*)d_in[5];
    const float* bhh0    = (const float*)d_in[6];
    const float* Wih1f   = (const float*)d_in[7];
    const float* Whh1f   = (const float*)d_in[8];
    const float* bih1    = (const float*)d_in[9];
    const float* bhh1    = (const float*)d_in[10];
    const float* dec_wf  = (const float*)d_in[11];
    const float* dec_b   = (const float*)d_in[12];
    const float* deconvw = (const float*)d_in[13];
    float* out = (float*)d_out;

    char* ws = (char*)d_ws;
    size_t off = 0;
    auto alloc = [&](size_t bytes) { char* p = ws + off; off = (off + bytes + 255) & ~(size_t)255; return p; };
    bf16*  seq   = (bf16*) alloc((size_t)T_ * B_ * F_ * 2);
    float* b0v   = (float*)alloc(G4H * 4);
    float* b1v   = (float*)alloc(G4H * 4);
    bf16*  h0    = (bf16*) alloc((size_t)3 * BH * 2);
    bf16*  h1    = (bf16*) alloc((size_t)3 * BH * 2);
    bf16*  y     = (bf16*) alloc((size_t)B_ * F_ * 2);
    float* fut   = (float*)alloc((size_t)B_ * F_ * NSTEPS_ * 4);
    bf16*  Wih0b = (bf16*) alloc((size_t)G4H * F_ * 2);
    bf16*  Whh0b = (bf16*) alloc((size_t)G4H * H_ * 2);
    bf16*  Wih1b = (bf16*) alloc((size_t)G4H * H_ * 2);
    bf16*  Whh1b = (bf16*) alloc((size_t)G4H * H_ * 2);
    bf16*  dec_wb= (bf16*) alloc((size_t)F_ * H_ * 2);
    int*   flags = (int*)  alloc(5 * 128 * STRF * 4);

    hipMemsetAsync(h0, 0, (size_t)3 * BH * 2, stream);
    hipMemsetAsync(h1, 0, (size_t)3 * BH * 2, stream);
    hipMemsetAsync(flags, 0, 5 * 128 * STRF * 4, stream);

    cvt_kernel<<<(G4H * F_ + 255) / 256, 256, 0, stream>>>(Wih0f, Wih0b, G4H * F_);
    cvt_kernel<<<(G4H * H_ + 255) / 256, 256, 0, stream>>>(Whh0f, Whh0b, G4H * H_);
    cvt_kernel<<<(G4H * H_ + 255) / 256, 256, 0, stream>>>(Wih1f, Wih1b, G4H * H_);
    cvt_kernel<<<(G4H * H_ + 255) / 256, 256, 0, stream>>>(Whh1f, Whh1b, G4H * H_);
    cvt_kernel<<<(F_ * H_ + 255) / 256, 256, 0, stream>>>(dec_wf, dec_wb, F_ * H_);

    bias_kernel<<<16, 256, 0, stream>>>(bih0, bhh0, bih1, bhh1, b0v, b1v);
    conv_kernel<<<B_, 256, 0, stream>>>(x, conv_w, conv_b, seq);

    PP P;
    P.seq = seq; P.Wih0 = Wih0b; P.Whh0 = Whh0b; P.Wih1 = Wih1b; P.Whh1 = Whh1b;
    P.dwb = dec_wb; P.b0 = b0v; P.b1 = b1v; P.dec_b = dec_b;
    P.fut = fut; P.h0 = h0; P.h1 = h1; P.y = y;
    P.flags = flags;

    void* args[] = { &P };
    hipError_t err = hipLaunchCooperativeKernel((const void*)lstm_persist,
                                                dim3(256), dim3(256), args, 0, stream);
    if (err != hipSuccess) {
        lstm_persist<<<256, 256, 0, stream>>>(P);
    }

    deconv_kernel<<<196, 256, 0, stream>>>(fut, deconvw, out);
}